// Round 16
// baseline (216.028 us; speedup 1.0000x reference)
//
#include <hip/hip_runtime.h>

#define NN 100000
#define NE 1600000
#define DF 128
#define NBUCK 391      // ceil(NN/256); bucket b = dst >> 8
#define PA_BLOCKS 196  // ceil(NE / 8192), 32 edges/thread @256
#define PB_BLOCKS 196  // ceil(NE / 8192), 16 edges/thread @512
#define CX_BLOCKS 3125 // NN*DF/8 / 512
#define CW_BLOCKS 64   // 128*256 / 512
#define AGG_GRID 3128  // ceil(NN/32) padded to %8==0 (NN%32==0: no tail nodes)
#define PC_LDS 6144    // bucket segment LDS capacity (mean 4096, sigma 64)

typedef short short8 __attribute__((ext_vector_type(8)));
typedef float floatx4 __attribute__((ext_vector_type(4)));
typedef float floatx2 __attribute__((ext_vector_type(2)));
typedef unsigned int uintx4 __attribute__((ext_vector_type(4)));
typedef unsigned int uint;
typedef unsigned short ushort;
typedef unsigned char uchar;

// float -> bf16 (RNE; inputs finite)
static __device__ __forceinline__ ushort f2bf(float f) {
    uint u = __builtin_bit_cast(uint, f);
    return (ushort)((u + 0x7fffu + ((u >> 16) & 1u)) >> 16);
}

// ---------------------------------------------------------------------------
// Atomic-free CSR build (R12/R13): per-edge rank + per-block histogram, scans,
// deterministic packed scatter. pairs = ((dst&255)<<17 | src), 4B.
// ---------------------------------------------------------------------------
__global__ __launch_bounds__(256) void pA_hist(const int* __restrict__ dst,
                                               int* __restrict__ hist,
                                               ushort* __restrict__ rank8) {
    __shared__ int h[NBUCK];
    int tid = threadIdx.x;
    for (int i = tid; i < NBUCK; i += 256) h[i] = 0;
    __syncthreads();
    int eb = blockIdx.x * 8192 + tid;
    #pragma unroll
    for (int k = 0; k < 32; ++k) {
        int e = eb + k * 256;
        if (e < NE) {
            int r = atomicAdd(&h[dst[e] >> 8], 1);
            rank8[e] = (ushort)r;               // rank within (block,bucket)
        }
    }
    __syncthreads();
    int* hrow = hist + blockIdx.x * NBUCK;
    for (int i = tid; i < NBUCK; i += 256) hrow[i] = h[i];
}

// Per-bucket exclusive scan over the 196 block rows: hist -> rel (in place),
// column total -> gt[b]. hist is 306KB, L2-resident.
__global__ __launch_bounds__(256) void pS2_colscan(int* __restrict__ hist,
                                                   int* __restrict__ gt) {
    __shared__ int ps[256];
    int b = blockIdx.x;
    int tid = threadIdx.x;
    int v = (tid < PA_BLOCKS) ? hist[tid * NBUCK + b] : 0;
    ps[tid] = v;
    __syncthreads();
    for (int st = 1; st < 256; st <<= 1) {
        int t = (tid >= st) ? ps[tid - st] : 0;
        __syncthreads();
        ps[tid] += t;
        __syncthreads();
    }
    if (tid < PA_BLOCKS) hist[tid * NBUCK + b] = ps[tid] - v;
    if (tid == 255) gt[b] = ps[255];            // column total
}

// Pass S: exclusive scan of bucket totals -> goff.
__global__ __launch_bounds__(512) void pS_scan(const int* __restrict__ gt,
                                               int* __restrict__ goff) {
    __shared__ int s[512];
    int tid = threadIdx.x;
    int v = (tid < NBUCK) ? gt[tid] : 0;
    s[tid] = v;
    __syncthreads();
    for (int st = 1; st < 512; st <<= 1) {
        int t = (tid >= st) ? s[tid - st] : 0;
        __syncthreads();
        s[tid] += t;
        __syncthreads();
    }
    if (tid < NBUCK) goff[tid] = s[tid] - v;
    if (tid == 0) goff[NBUCK] = NE;
}

// ---------------------------------------------------------------------------
// fused_mid: pB (deterministic 4B-pair scatter) overlapped with conv_x+conv_w.
// ---------------------------------------------------------------------------
__global__ __launch_bounds__(512) void fused_mid(
        const int* __restrict__ src, const int* __restrict__ dst,
        const ushort* __restrict__ rank8, const int* __restrict__ rel,
        const int* __restrict__ goff, uint* __restrict__ pairs,
        const float* __restrict__ x, ushort* __restrict__ xb, uint* __restrict__ xf8,
        const float* __restrict__ W1l, const float* __restrict__ W1r,
        const float* __restrict__ W2l, const float* __restrict__ W2r,
        ushort* __restrict__ WT1, ushort* __restrict__ WT2) {
    __shared__ int lbase[NBUCK];
    int bid = blockIdx.x;
    int tid = threadIdx.x;
    if (bid < PB_BLOCKS) {
        const int* rel_row = rel + bid * NBUCK;
        for (int i = tid; i < NBUCK; i += 512) lbase[i] = goff[i] + rel_row[i];
        __syncthreads();
        int eb = bid * 8192 + tid;
        #pragma unroll
        for (int k = 0; k < 16; ++k) {
            int e = eb + k * 512;
            if (e < NE) {
                int s = src[e];
                int d = dst[e];
                int b = d >> 8;
                int pos = lbase[b] + (int)rank8[e];
                pairs[pos] = ((uint)(d & 255) << 17) | (uint)s;
            }
        }
    } else if (bid < PB_BLOCKS + CX_BLOCKS) {
        int j = (bid - PB_BLOCKS) * 512 + tid;   // elem group [j*8, j*8+8)
        const float4* xr = (const float4*)x + (size_t)j * 2;
        float4 v0 = xr[0], v1 = xr[1];
        uint4 ob;
        ob.x = (uint)f2bf(v0.x) | ((uint)f2bf(v0.y) << 16);
        ob.y = (uint)f2bf(v0.z) | ((uint)f2bf(v0.w) << 16);
        ob.z = (uint)f2bf(v1.x) | ((uint)f2bf(v1.y) << 16);
        ob.w = (uint)f2bf(v1.z) | ((uint)f2bf(v1.w) << 16);
        ((uint4*)xb)[j] = ob;
        uint pk0 = (uint)__builtin_amdgcn_cvt_pk_fp8_f32(v0.x, v0.y, 0, false);
        pk0 = (uint)__builtin_amdgcn_cvt_pk_fp8_f32(v0.z, v0.w, (int)pk0, true);
        uint pk1 = (uint)__builtin_amdgcn_cvt_pk_fp8_f32(v1.x, v1.y, 0, false);
        pk1 = (uint)__builtin_amdgcn_cvt_pk_fp8_f32(v1.z, v1.w, (int)pk1, true);
        ((uint2*)xf8)[j] = make_uint2(pk0, pk1);
    } else {
        int id = (bid - PB_BLOCKS - CX_BLOCKS) * 512 + tid;
        int n = id >> 8, k = id & 255;
        float a = (k < 128) ? W1l[k * 128 + n] : W1r[(k - 128) * 128 + n];
        float b = (k < 128) ? W2l[k * 128 + n] : W2r[(k - 128) * 128 + n];
        WT1[id] = f2bf(a);
        WT2[id] = f2bf(b);
    }
}

// ---------------------------------------------------------------------------
// Pass C, R15: scatter the bucket segment into LDS, SORT each node's
// sub-segment by src (1 thread/node insertion sort), write srt coalesced.
// Sorted segments make every agg block walk src-space monotonically ->
// co-resident blocks' gathers concentrate in a sliding L2-resident window
// (the gather stream was random over 12.8MB >> 4MB/XCD L2 -> L3 latency).
// One-time cost, amortized over BOTH agg layers. Fallback: unsorted direct
// scatter if segment > PC_LDS (>+32 sigma, effectively never).
// ---------------------------------------------------------------------------
__global__ __launch_bounds__(256) void pC_scatter(const uint* __restrict__ pairs,
                                                  const int* __restrict__ goff,
                                                  int* __restrict__ off,
                                                  int* __restrict__ srt) {
    __shared__ int deg[256];
    __shared__ int loc[256];
    __shared__ int nbase[256];
    __shared__ int lsrt[PC_LDS];
    int b = blockIdx.x;
    int beg = goff[b], end = goff[b + 1];
    int seglen = end - beg;
    int tid = threadIdx.x;
    deg[tid] = 0;
    __syncthreads();
    for (int i = beg + tid; i < end; i += 256)
        atomicAdd(&deg[pairs[i] >> 17], 1);
    __syncthreads();
    int v = deg[tid];
    loc[tid] = v;
    __syncthreads();
    for (int st = 1; st < 256; st <<= 1) {
        int t = (tid >= st) ? loc[tid - st] : 0;
        __syncthreads();
        loc[tid] += t;
        __syncthreads();
    }
    int excl = loc[tid] - v;           // node sub-segment base, relative to beg
    int n = (b << 8) + tid;
    if (n < NN) off[n] = beg + excl;
    nbase[tid] = excl;
    __syncthreads();
    if (seglen <= PC_LDS) {
        deg[tid] = excl;               // reuse as relative cursor
        __syncthreads();
        for (int i = beg + tid; i < end; i += 256) {
            uint pr = pairs[i];
            int pos = atomicAdd(&deg[pr >> 17], 1);
            lsrt[pos] = (int)(pr & 0x1FFFFu);
        }
        __syncthreads();
        // insertion-sort node tid's sub-segment [nbase, nbase+v)
        int s0 = nbase[tid], s1 = s0 + v;
        for (int i = s0 + 1; i < s1; ++i) {
            int key = lsrt[i];
            int j = i - 1;
            while (j >= s0 && lsrt[j] > key) {
                lsrt[j + 1] = lsrt[j];
                --j;
            }
            lsrt[j + 1] = key;
        }
        __syncthreads();
        for (int i = tid; i < seglen; i += 256)
            srt[beg + i] = lsrt[i];
    } else {                           // fallback: unsorted direct scatter
        deg[tid] = beg + excl;
        __syncthreads();
        for (int i = beg + tid; i < end; i += 256) {
            uint pr = pairs[i];
            int pos = atomicAdd(&deg[pr >> 17], 1);
            srt[pos] = (int)(pr & 0x1FFFFu);
        }
    }
}

// ---------------------------------------------------------------------------
// Mean aggregation, SINGLE PASS over row-major fp8 (R11/R13 design; R14's
// wave balancing reverted — measured neutral). srt now src-sorted per node.
// ---------------------------------------------------------------------------
static __device__ __forceinline__ void acc16(floatx2* ac, uint4 v) {
    ac[0] += __builtin_amdgcn_cvt_pk_f32_fp8((int)v.x, false);
    ac[1] += __builtin_amdgcn_cvt_pk_f32_fp8((int)v.x, true);
    ac[2] += __builtin_amdgcn_cvt_pk_f32_fp8((int)v.y, false);
    ac[3] += __builtin_amdgcn_cvt_pk_f32_fp8((int)v.y, true);
    ac[4] += __builtin_amdgcn_cvt_pk_f32_fp8((int)v.z, false);
    ac[5] += __builtin_amdgcn_cvt_pk_f32_fp8((int)v.z, true);
    ac[6] += __builtin_amdgcn_cvt_pk_f32_fp8((int)v.w, false);
    ac[7] += __builtin_amdgcn_cvt_pk_f32_fp8((int)v.w, true);
}

#define AGG_LOOP(IDX)                                            \
    {                                                            \
        int i = lb;                                              \
        for (; i + 8 <= le; i += 8) {                            \
            int idx[8];                                          \
            _Pragma("unroll")                                    \
            for (int k = 0; k < 8; ++k) idx[k] = IDX(i + k);     \
            uint4 v[8];                                          \
            _Pragma("unroll")                                    \
            for (int k = 0; k < 8; ++k) v[k] = f[(size_t)idx[k] * 8]; \
            _Pragma("unroll")                                    \
            for (int k = 0; k < 8; ++k) acc16(ac, v[k]);         \
        }                                                        \
        if (i + 4 <= le) {                                       \
            int idx[4];                                          \
            _Pragma("unroll")                                    \
            for (int k = 0; k < 4; ++k) idx[k] = IDX(i + k);     \
            uint4 v[4];                                          \
            _Pragma("unroll")                                    \
            for (int k = 0; k < 4; ++k) v[k] = f[(size_t)idx[k] * 8]; \
            _Pragma("unroll")                                    \
            for (int k = 0; k < 4; ++k) acc16(ac, v[k]);         \
            i += 4;                                              \
        }                                                        \
        for (; i < le; ++i) {                                    \
            uint4 v = f[(size_t)IDX(i) * 8];                     \
            acc16(ac, v);                                        \
        }                                                        \
    }

__global__ __launch_bounds__(256) void agg_csr(const uint* __restrict__ feat8,
                                               const int* __restrict__ srt,
                                               const int* __restrict__ off,
                                               ushort* __restrict__ aggb) {
    __shared__ int sidx[2048];
    int nb = blockIdx.x * 32;
    if (nb >= NN) return;                        // uniform per block; NN%32==0
    int tid = threadIdx.x;

    int segb = off[nb];
    int nend = nb + 32;
    int sege = (nend < NN) ? off[nend] : NE;
    int stage = min(sege - segb, 2048);
    for (int i = tid; i < stage; i += 256) sidx[i] = srt[segb + i];
    __syncthreads();

    int n = nb + (tid >> 3);
    int l = tid & 7;
    const uint4* f = (const uint4*)feat8 + l;    // row stride = 8 uint4 (128B)

    int beg = off[n];
    int end = (n < NN - 1) ? off[n + 1] : NE;
    int lb = beg - segb, le = end - segb;

    floatx2 ac[8];
    #pragma unroll
    for (int t = 0; t < 8; ++t) ac[t] = (floatx2){0.f, 0.f};

    if (le <= stage) {
        #define IDX_LDS(ii) sidx[ii]
        AGG_LOOP(IDX_LDS)
        #undef IDX_LDS
    } else {
        #define IDX_GBL(ii) srt[segb + (ii)]
        AGG_LOOP(IDX_GBL)
        #undef IDX_GBL
    }

    float inv = 1.0f / fmaxf((float)(end - beg), 1.0f);
    uintx4 o0, o1;
    o0.x = (uint)f2bf(ac[0].x * inv) | ((uint)f2bf(ac[0].y * inv) << 16);
    o0.y = (uint)f2bf(ac[1].x * inv) | ((uint)f2bf(ac[1].y * inv) << 16);
    o0.z = (uint)f2bf(ac[2].x * inv) | ((uint)f2bf(ac[2].y * inv) << 16);
    o0.w = (uint)f2bf(ac[3].x * inv) | ((uint)f2bf(ac[3].y * inv) << 16);
    o1.x = (uint)f2bf(ac[4].x * inv) | ((uint)f2bf(ac[4].y * inv) << 16);
    o1.y = (uint)f2bf(ac[5].x * inv) | ((uint)f2bf(ac[5].y * inv) << 16);
    o1.z = (uint)f2bf(ac[6].x * inv) | ((uint)f2bf(ac[6].y * inv) << 16);
    o1.w = (uint)f2bf(ac[7].x * inv) | ((uint)f2bf(ac[7].y * inv) << 16);
    uintx4* dp = (uintx4*)(aggb + (size_t)n * 128 + l * 16);
    __builtin_nontemporal_store(o0, dp);
    __builtin_nontemporal_store(o1, dp + 1);
}

// ---------------------------------------------------------------------------
// Fused GEMM: C[n,j] = act( [agg|self][n,:] @ WT[j,:] + bias[j] ), K=256.
// 512 threads = 8 waves, 128 rows/block. WT staged in LDS (XOR swizzle, 64KB).
// F8OUT: emit fp8 ROW-MAJOR (single-pass agg input) -> contiguous epilogue.
// ---------------------------------------------------------------------------
template <int RELU, int BF16OUT, int F8OUT>
__global__ __launch_bounds__(512, 4) void gemm_mfma(
        const ushort* __restrict__ aggb, const ushort* __restrict__ selfb,
        const ushort* __restrict__ WT, const float* __restrict__ bias,
        void* __restrict__ outv, uchar* __restrict__ f8out) {
    __shared__ ushort sWT[128 * 256];            // 64KB, swizzled chunks
    const int tid = threadIdx.x;
    const int blk = blockIdx.x;

    #pragma unroll
    for (int it = 0; it < 8; ++it) {
        int flat = it * 512 + tid;               // 0..4095
        int col = flat >> 5;
        int c = flat & 31;
        uint4 v = *(const uint4*)(WT + (size_t)col * 256 + c * 8);
        *(uint4*)&sWT[col * 256 + (c ^ (col & 7)) * 8] = v;
    }

    const int w = tid >> 6;
    const int lane = tid & 63;
    const int m = lane & 15;
    const int q = lane >> 4;

    int node_m = blk * 128 + w * 16 + m;
    int cn = node_m < NN ? node_m : NN - 1;
    const ushort* arow = aggb + (size_t)cn * 128;
    const ushort* xrow = selfb + (size_t)cn * 128;
    short8 a[8];
    #pragma unroll
    for (int kk = 0; kk < 4; ++kk) {
        a[kk]     = *(const short8*)(arow + kk * 32 + q * 8);
        a[4 + kk] = *(const short8*)(xrow + kk * 32 + q * 8);
    }

    __syncthreads();

    floatx4 acc[8];
    #pragma unroll
    for (int t = 0; t < 8; ++t) acc[t] = (floatx4){0.f, 0.f, 0.f, 0.f};

    const int m7 = m & 7;
    #pragma unroll
    for (int kk = 0; kk < 8; ++kk) {
        int cx = (kk * 4 + q) ^ m7;
        #pragma unroll
        for (int t = 0; t < 8; ++t) {
            short8 b = *(const short8*)&sWT[(t * 16 + m) * 256 + cx * 8];
            acc[t] = __builtin_amdgcn_mfma_f32_16x16x32_bf16(a[kk], b, acc[t], 0, 0, 0);
        }
    }

    const int node_base = blk * 128 + w * 16 + q * 4;
    #pragma unroll
    for (int t = 0; t < 8; ++t) {
        int col = t * 16 + m;
        float bj = bias[col];
        #pragma unroll
        for (int r = 0; r < 4; ++r) {
            int node = node_base + r;
            if (node < NN) {
                float v = acc[t][r] + bj;
                if (RELU) v = fmaxf(v, 0.0f);
                if (BF16OUT)
                    ((ushort*)outv)[(size_t)node * 128 + col] = f2bf(v);
                else
                    ((float*)outv)[(size_t)node * 128 + col] = v;
                if (F8OUT) {
                    uint pk = (uint)__builtin_amdgcn_cvt_pk_fp8_f32(v, v, 0, false);
                    f8out[(size_t)node * 128 + col] = (uchar)pk;
                }
            }
        }
    }
}

// ---------------------------------------------------------------------------
extern "C" void kernel_launch(void* const* d_in, const int* in_sizes, int n_in,
                              void* d_out, int out_size, void* d_ws, size_t ws_size,
                              hipStream_t stream) {
    const float* x   = (const float*)d_in[0];
    const int*   ei  = (const int*)d_in[1];
    const float* W1l = (const float*)d_in[2];
    const float* b1  = (const float*)d_in[3];
    const float* W1r = (const float*)d_in[4];
    const float* W2l = (const float*)d_in[5];
    const float* b2  = (const float*)d_in[6];
    const float* W2r = (const float*)d_in[7];
    float*       out = (float*)d_out;

    const int* src = ei;
    const int* dst = ei + NE;

    // workspace layout (bytes), total 96.93 MB
    char* ws = (char*)d_ws;
    int*    off  = (int*)(ws);                   // 400000
    int*    srt  = (int*)(ws + 400000);          // 6400000 (ends 6.8MB)
    ushort* WT1  = (ushort*)(ws + 7200000);      // 65536
    ushort* WT2  = (ushort*)(ws + 7265536);      // 65536
    ushort* xb   = (ushort*)(ws + 7331072);      // 25600000
    uint*   xf8  = (uint*)(ws + 32931072);       // 12800000 (row-major fp8)
    ushort* aggb = (ushort*)(ws + 45731072);     // 25600000
    ushort* hb   = (ushort*)(ws + 71331072);     // 25600000 (end 96.93MB)
    uchar*  hf8  = (uchar*)xf8;                  // alias: xf8 dead after agg L1
    // CSR-build temporaries (alias aggb region, all dead before agg writes it):
    uint*   pairs = (uint*)aggb;                         // 6400000 (packed 4B)
    int*    hist  = (int*)((char*)aggb + 6400000);       // 196*391*4 = 306544
    ushort* rank8 = (ushort*)((char*)aggb + 6720000);    // 3200000
    int*    gt    = (int*)((char*)aggb + 9920512);       // 1564
    int*    goff  = (int*)((char*)aggb + 9922304);       // 1568

    // ---- CSR build (atomic-free, packed, src-sorted segments) ----
    pA_hist<<<PA_BLOCKS, 256, 0, stream>>>(dst, hist, rank8);
    pS2_colscan<<<NBUCK, 256, 0, stream>>>(hist, gt);
    pS_scan<<<1, 512, 0, stream>>>(gt, goff);
    fused_mid<<<PB_BLOCKS + CX_BLOCKS + CW_BLOCKS, 512, 0, stream>>>(
        src, dst, rank8, hist, goff, pairs, x, xb, xf8,
        W1l, W1r, W2l, W2r, WT1, WT2);
    pC_scatter<<<NBUCK, 256, 0, stream>>>(pairs, goff, off, srt);

    const int gemm_grid = (NN + 127) / 128;

    // ---- layer 1 ----  (single-pass agg: every edge row gathered once)
    agg_csr<<<AGG_GRID, 256, 0, stream>>>(xf8, srt, off, aggb);
    gemm_mfma<1, 1, 1><<<gemm_grid, 512, 0, stream>>>(aggb, xb, WT1, b1, hb, hf8);

    // ---- layer 2 ----
    agg_csr<<<AGG_GRID, 256, 0, stream>>>((const uint*)hf8, srt, off, aggb);
    gemm_mfma<0, 0, 0><<<gemm_grid, 512, 0, stream>>>(aggb, hb, WT2, b2, out, nullptr);
}

// Round 18
// 194.562 us; speedup vs baseline: 1.1103x; 1.1103x over previous
//
#include <hip/hip_runtime.h>

#define NN 100000
#define NE 1600000
#define DF 128
#define NBUCK 391      // ceil(NN/256); bucket b = dst >> 8
#define PA_BLOCKS 196  // ceil(NE / 8192), 32 edges/thread @256
#define PB_BLOCKS 196  // ceil(NE / 8192), 16 edges/thread @512
#define CX_BLOCKS 3125 // NN*DF/8 / 512
#define CW_BLOCKS 64   // 128*256 / 512
#define AGG_GRID 3128  // ceil(NN/32) padded to %8==0 (NN%32==0: no tail nodes)
#define PC_LDS 6144    // bucket segment LDS capacity (mean 4096, sigma 64)

typedef short short8 __attribute__((ext_vector_type(8)));
typedef float floatx4 __attribute__((ext_vector_type(4)));
typedef float floatx2 __attribute__((ext_vector_type(2)));
typedef unsigned int uintx4 __attribute__((ext_vector_type(4)));
typedef unsigned int uint;
typedef unsigned short ushort;
typedef unsigned char uchar;

// float -> bf16 (RNE; inputs finite)
static __device__ __forceinline__ ushort f2bf(float f) {
    uint u = __builtin_bit_cast(uint, f);
    return (ushort)((u + 0x7fffu + ((u >> 16) & 1u)) >> 16);
}

// ---------------------------------------------------------------------------
// Atomic-free CSR build (R12/R13): per-edge rank + per-block histogram, scans,
// deterministic packed scatter. pairs = ((dst&255)<<17 | src), 4B.
// ---------------------------------------------------------------------------
__global__ __launch_bounds__(256) void pA_hist(const int* __restrict__ dst,
                                               int* __restrict__ hist,
                                               ushort* __restrict__ rank8) {
    __shared__ int h[NBUCK];
    int tid = threadIdx.x;
    for (int i = tid; i < NBUCK; i += 256) h[i] = 0;
    __syncthreads();
    int eb = blockIdx.x * 8192 + tid;
    #pragma unroll
    for (int k = 0; k < 32; ++k) {
        int e = eb + k * 256;
        if (e < NE) {
            int r = atomicAdd(&h[dst[e] >> 8], 1);
            rank8[e] = (ushort)r;               // rank within (block,bucket)
        }
    }
    __syncthreads();
    int* hrow = hist + blockIdx.x * NBUCK;
    for (int i = tid; i < NBUCK; i += 256) hrow[i] = h[i];
}

// Per-bucket exclusive scan over the 196 block rows: hist -> rel (in place),
// column total -> gt[b]. hist is 306KB, L2-resident.
__global__ __launch_bounds__(256) void pS2_colscan(int* __restrict__ hist,
                                                   int* __restrict__ gt) {
    __shared__ int ps[256];
    int b = blockIdx.x;
    int tid = threadIdx.x;
    int v = (tid < PA_BLOCKS) ? hist[tid * NBUCK + b] : 0;
    ps[tid] = v;
    __syncthreads();
    for (int st = 1; st < 256; st <<= 1) {
        int t = (tid >= st) ? ps[tid - st] : 0;
        __syncthreads();
        ps[tid] += t;
        __syncthreads();
    }
    if (tid < PA_BLOCKS) hist[tid * NBUCK + b] = ps[tid] - v;
    if (tid == 255) gt[b] = ps[255];            // column total
}

// Pass S: exclusive scan of bucket totals -> goff.
__global__ __launch_bounds__(512) void pS_scan(const int* __restrict__ gt,
                                               int* __restrict__ goff) {
    __shared__ int s[512];
    int tid = threadIdx.x;
    int v = (tid < NBUCK) ? gt[tid] : 0;
    s[tid] = v;
    __syncthreads();
    for (int st = 1; st < 512; st <<= 1) {
        int t = (tid >= st) ? s[tid - st] : 0;
        __syncthreads();
        s[tid] += t;
        __syncthreads();
    }
    if (tid < NBUCK) goff[tid] = s[tid] - v;
    if (tid == 0) goff[NBUCK] = NE;
}

// ---------------------------------------------------------------------------
// fused_mid: pB (deterministic 4B-pair scatter) overlapped with conv_x+conv_w.
// ---------------------------------------------------------------------------
__global__ __launch_bounds__(512) void fused_mid(
        const int* __restrict__ src, const int* __restrict__ dst,
        const ushort* __restrict__ rank8, const int* __restrict__ rel,
        const int* __restrict__ goff, uint* __restrict__ pairs,
        const float* __restrict__ x, ushort* __restrict__ xb, uint* __restrict__ xf8,
        const float* __restrict__ W1l, const float* __restrict__ W1r,
        const float* __restrict__ W2l, const float* __restrict__ W2r,
        ushort* __restrict__ WT1, ushort* __restrict__ WT2) {
    __shared__ int lbase[NBUCK];
    int bid = blockIdx.x;
    int tid = threadIdx.x;
    if (bid < PB_BLOCKS) {
        const int* rel_row = rel + bid * NBUCK;
        for (int i = tid; i < NBUCK; i += 512) lbase[i] = goff[i] + rel_row[i];
        __syncthreads();
        int eb = bid * 8192 + tid;
        #pragma unroll
        for (int k = 0; k < 16; ++k) {
            int e = eb + k * 512;
            if (e < NE) {
                int s = src[e];
                int d = dst[e];
                int b = d >> 8;
                int pos = lbase[b] + (int)rank8[e];
                pairs[pos] = ((uint)(d & 255) << 17) | (uint)s;
            }
        }
    } else if (bid < PB_BLOCKS + CX_BLOCKS) {
        int j = (bid - PB_BLOCKS) * 512 + tid;   // elem group [j*8, j*8+8)
        const float4* xr = (const float4*)x + (size_t)j * 2;
        float4 v0 = xr[0], v1 = xr[1];
        uint4 ob;
        ob.x = (uint)f2bf(v0.x) | ((uint)f2bf(v0.y) << 16);
        ob.y = (uint)f2bf(v0.z) | ((uint)f2bf(v0.w) << 16);
        ob.z = (uint)f2bf(v1.x) | ((uint)f2bf(v1.y) << 16);
        ob.w = (uint)f2bf(v1.z) | ((uint)f2bf(v1.w) << 16);
        ((uint4*)xb)[j] = ob;
        uint pk0 = (uint)__builtin_amdgcn_cvt_pk_fp8_f32(v0.x, v0.y, 0, false);
        pk0 = (uint)__builtin_amdgcn_cvt_pk_fp8_f32(v0.z, v0.w, (int)pk0, true);
        uint pk1 = (uint)__builtin_amdgcn_cvt_pk_fp8_f32(v1.x, v1.y, 0, false);
        pk1 = (uint)__builtin_amdgcn_cvt_pk_fp8_f32(v1.z, v1.w, (int)pk1, true);
        ((uint2*)xf8)[j] = make_uint2(pk0, pk1);
    } else {
        int id = (bid - PB_BLOCKS - CX_BLOCKS) * 512 + tid;
        int n = id >> 8, k = id & 255;
        float a = (k < 128) ? W1l[k * 128 + n] : W1r[(k - 128) * 128 + n];
        float b = (k < 128) ? W2l[k * 128 + n] : W2r[(k - 128) * 128 + n];
        WT1[id] = f2bf(a);
        WT2[id] = f2bf(b);
    }
}

// ---------------------------------------------------------------------------
// Pass C, R17: LDS scatter of packed (node|src) + PARALLEL RANK-COUNT sort
// (R16's per-node insertion sort was 54us: serial O(d^2) LDS chains + 1.69M
// bank conflicts; the sorted-segment agg gain of ~14us was real). Each
// ELEMENT computes its rank within its node's sub-segment (d~16 independent
// pipelined LDS reads) and stores to srt[beg+s0+rank] — global stores land
// in the bucket's 16KB window (block-local dirtying, no amplification).
// Fallback: unsorted direct scatter if segment > PC_LDS (effectively never).
// ---------------------------------------------------------------------------
__global__ __launch_bounds__(256) void pC_scatter(const uint* __restrict__ pairs,
                                                  const int* __restrict__ goff,
                                                  int* __restrict__ off,
                                                  int* __restrict__ srt) {
    __shared__ int degv[256];
    __shared__ int loc[256];
    __shared__ int nbase[256];
    __shared__ uint lsrt[PC_LDS];
    int b = blockIdx.x;
    int beg = goff[b], end = goff[b + 1];
    int seglen = end - beg;
    int tid = threadIdx.x;
    degv[tid] = 0;
    __syncthreads();
    for (int i = beg + tid; i < end; i += 256)
        atomicAdd(&degv[pairs[i] >> 17], 1);
    __syncthreads();
    int v = degv[tid];
    loc[tid] = v;
    __syncthreads();
    for (int st = 1; st < 256; st <<= 1) {
        int t = (tid >= st) ? loc[tid - st] : 0;
        __syncthreads();
        loc[tid] += t;
        __syncthreads();
    }
    int excl = loc[tid] - v;           // node sub-segment base, relative to beg
    int n = (b << 8) + tid;
    if (n < NN) off[n] = beg + excl;
    nbase[tid] = excl;
    __syncthreads();
    loc[tid] = excl;                   // reuse as relative cursor
    __syncthreads();
    if (seglen <= PC_LDS) {
        // scatter packed values into LDS (node kept for the rank pass)
        for (int i = beg + tid; i < end; i += 256) {
            uint pr = pairs[i];
            int pos = atomicAdd(&loc[pr >> 17], 1);
            lsrt[pos] = pr;
        }
        __syncthreads();
        // rank-count: element i's rank within its node's sub-segment
        for (int i = tid; i < seglen; i += 256) {
            uint val = lsrt[i];
            int node = (int)(val >> 17);
            uint sv = val & 0x1FFFFu;
            int s0 = nbase[node];
            int d = degv[node];
            int rank = 0;
            for (int k = s0; k < s0 + d; ++k) {
                uint wv = lsrt[k] & 0x1FFFFu;
                rank += (wv < sv) || (wv == sv && k < i);
            }
            srt[beg + s0 + rank] = (int)sv;
        }
    } else {                           // fallback: unsorted direct scatter
        for (int i = beg + tid; i < end; i += 256) {
            uint pr = pairs[i];
            int pos = atomicAdd(&loc[pr >> 17], 1);
            srt[beg + pos] = (int)(pr & 0x1FFFFu);
        }
    }
}

// ---------------------------------------------------------------------------
// Mean aggregation, SINGLE PASS over row-major fp8 (R11/R13 design).
// srt is src-sorted per node -> chip-wide sliding-window gather locality.
// ---------------------------------------------------------------------------
static __device__ __forceinline__ void acc16(floatx2* ac, uint4 v) {
    ac[0] += __builtin_amdgcn_cvt_pk_f32_fp8((int)v.x, false);
    ac[1] += __builtin_amdgcn_cvt_pk_f32_fp8((int)v.x, true);
    ac[2] += __builtin_amdgcn_cvt_pk_f32_fp8((int)v.y, false);
    ac[3] += __builtin_amdgcn_cvt_pk_f32_fp8((int)v.y, true);
    ac[4] += __builtin_amdgcn_cvt_pk_f32_fp8((int)v.z, false);
    ac[5] += __builtin_amdgcn_cvt_pk_f32_fp8((int)v.z, true);
    ac[6] += __builtin_amdgcn_cvt_pk_f32_fp8((int)v.w, false);
    ac[7] += __builtin_amdgcn_cvt_pk_f32_fp8((int)v.w, true);
}

#define AGG_LOOP(IDX)                                            \
    {                                                            \
        int i = lb;                                              \
        for (; i + 8 <= le; i += 8) {                            \
            int idx[8];                                          \
            _Pragma("unroll")                                    \
            for (int k = 0; k < 8; ++k) idx[k] = IDX(i + k);     \
            uint4 v[8];                                          \
            _Pragma("unroll")                                    \
            for (int k = 0; k < 8; ++k) v[k] = f[(size_t)idx[k] * 8]; \
            _Pragma("unroll")                                    \
            for (int k = 0; k < 8; ++k) acc16(ac, v[k]);         \
        }                                                        \
        if (i + 4 <= le) {                                       \
            int idx[4];                                          \
            _Pragma("unroll")                                    \
            for (int k = 0; k < 4; ++k) idx[k] = IDX(i + k);     \
            uint4 v[4];                                          \
            _Pragma("unroll")                                    \
            for (int k = 0; k < 4; ++k) v[k] = f[(size_t)idx[k] * 8]; \
            _Pragma("unroll")                                    \
            for (int k = 0; k < 4; ++k) acc16(ac, v[k]);         \
            i += 4;                                              \
        }                                                        \
        for (; i < le; ++i) {                                    \
            uint4 v = f[(size_t)IDX(i) * 8];                     \
            acc16(ac, v);                                        \
        }                                                        \
    }

__global__ __launch_bounds__(256) void agg_csr(const uint* __restrict__ feat8,
                                               const int* __restrict__ srt,
                                               const int* __restrict__ off,
                                               ushort* __restrict__ aggb) {
    __shared__ int sidx[2048];
    int nb = blockIdx.x * 32;
    if (nb >= NN) return;                        // uniform per block; NN%32==0
    int tid = threadIdx.x;

    int segb = off[nb];
    int nend = nb + 32;
    int sege = (nend < NN) ? off[nend] : NE;
    int stage = min(sege - segb, 2048);
    for (int i = tid; i < stage; i += 256) sidx[i] = srt[segb + i];
    __syncthreads();

    int n = nb + (tid >> 3);
    int l = tid & 7;
    const uint4* f = (const uint4*)feat8 + l;    // row stride = 8 uint4 (128B)

    int beg = off[n];
    int end = (n < NN - 1) ? off[n + 1] : NE;
    int lb = beg - segb, le = end - segb;

    floatx2 ac[8];
    #pragma unroll
    for (int t = 0; t < 8; ++t) ac[t] = (floatx2){0.f, 0.f};

    if (le <= stage) {
        #define IDX_LDS(ii) sidx[ii]
        AGG_LOOP(IDX_LDS)
        #undef IDX_LDS
    } else {
        #define IDX_GBL(ii) srt[segb + (ii)]
        AGG_LOOP(IDX_GBL)
        #undef IDX_GBL
    }

    float inv = 1.0f / fmaxf((float)(end - beg), 1.0f);
    uintx4 o0, o1;
    o0.x = (uint)f2bf(ac[0].x * inv) | ((uint)f2bf(ac[0].y * inv) << 16);
    o0.y = (uint)f2bf(ac[1].x * inv) | ((uint)f2bf(ac[1].y * inv) << 16);
    o0.z = (uint)f2bf(ac[2].x * inv) | ((uint)f2bf(ac[2].y * inv) << 16);
    o0.w = (uint)f2bf(ac[3].x * inv) | ((uint)f2bf(ac[3].y * inv) << 16);
    o1.x = (uint)f2bf(ac[4].x * inv) | ((uint)f2bf(ac[4].y * inv) << 16);
    o1.y = (uint)f2bf(ac[5].x * inv) | ((uint)f2bf(ac[5].y * inv) << 16);
    o1.z = (uint)f2bf(ac[6].x * inv) | ((uint)f2bf(ac[6].y * inv) << 16);
    o1.w = (uint)f2bf(ac[7].x * inv) | ((uint)f2bf(ac[7].y * inv) << 16);
    uintx4* dp = (uintx4*)(aggb + (size_t)n * 128 + l * 16);
    __builtin_nontemporal_store(o0, dp);
    __builtin_nontemporal_store(o1, dp + 1);
}

// ---------------------------------------------------------------------------
// Fused GEMM: C[n,j] = act( [agg|self][n,:] @ WT[j,:] + bias[j] ), K=256.
// 512 threads = 8 waves, 128 rows/block. WT staged in LDS (XOR swizzle, 64KB).
// F8OUT: emit fp8 ROW-MAJOR (single-pass agg input) -> contiguous epilogue.
// ---------------------------------------------------------------------------
template <int RELU, int BF16OUT, int F8OUT>
__global__ __launch_bounds__(512, 4) void gemm_mfma(
        const ushort* __restrict__ aggb, const ushort* __restrict__ selfb,
        const ushort* __restrict__ WT, const float* __restrict__ bias,
        void* __restrict__ outv, uchar* __restrict__ f8out) {
    __shared__ ushort sWT[128 * 256];            // 64KB, swizzled chunks
    const int tid = threadIdx.x;
    const int blk = blockIdx.x;

    #pragma unroll
    for (int it = 0; it < 8; ++it) {
        int flat = it * 512 + tid;               // 0..4095
        int col = flat >> 5;
        int c = flat & 31;
        uint4 v = *(const uint4*)(WT + (size_t)col * 256 + c * 8);
        *(uint4*)&sWT[col * 256 + (c ^ (col & 7)) * 8] = v;
    }

    const int w = tid >> 6;
    const int lane = tid & 63;
    const int m = lane & 15;
    const int q = lane >> 4;

    int node_m = blk * 128 + w * 16 + m;
    int cn = node_m < NN ? node_m : NN - 1;
    const ushort* arow = aggb + (size_t)cn * 128;
    const ushort* xrow = selfb + (size_t)cn * 128;
    short8 a[8];
    #pragma unroll
    for (int kk = 0; kk < 4; ++kk) {
        a[kk]     = *(const short8*)(arow + kk * 32 + q * 8);
        a[4 + kk] = *(const short8*)(xrow + kk * 32 + q * 8);
    }

    __syncthreads();

    floatx4 acc[8];
    #pragma unroll
    for (int t = 0; t < 8; ++t) acc[t] = (floatx4){0.f, 0.f, 0.f, 0.f};

    const int m7 = m & 7;
    #pragma unroll
    for (int kk = 0; kk < 8; ++kk) {
        int cx = (kk * 4 + q) ^ m7;
        #pragma unroll
        for (int t = 0; t < 8; ++t) {
            short8 b = *(const short8*)&sWT[(t * 16 + m) * 256 + cx * 8];
            acc[t] = __builtin_amdgcn_mfma_f32_16x16x32_bf16(a[kk], b, acc[t], 0, 0, 0);
        }
    }

    const int node_base = blk * 128 + w * 16 + q * 4;
    #pragma unroll
    for (int t = 0; t < 8; ++t) {
        int col = t * 16 + m;
        float bj = bias[col];
        #pragma unroll
        for (int r = 0; r < 4; ++r) {
            int node = node_base + r;
            if (node < NN) {
                float v = acc[t][r] + bj;
                if (RELU) v = fmaxf(v, 0.0f);
                if (BF16OUT)
                    ((ushort*)outv)[(size_t)node * 128 + col] = f2bf(v);
                else
                    ((float*)outv)[(size_t)node * 128 + col] = v;
                if (F8OUT) {
                    uint pk = (uint)__builtin_amdgcn_cvt_pk_fp8_f32(v, v, 0, false);
                    f8out[(size_t)node * 128 + col] = (uchar)pk;
                }
            }
        }
    }
}

// ---------------------------------------------------------------------------
extern "C" void kernel_launch(void* const* d_in, const int* in_sizes, int n_in,
                              void* d_out, int out_size, void* d_ws, size_t ws_size,
                              hipStream_t stream) {
    const float* x   = (const float*)d_in[0];
    const int*   ei  = (const int*)d_in[1];
    const float* W1l = (const float*)d_in[2];
    const float* b1  = (const float*)d_in[3];
    const float* W1r = (const float*)d_in[4];
    const float* W2l = (const float*)d_in[5];
    const float* b2  = (const float*)d_in[6];
    const float* W2r = (const float*)d_in[7];
    float*       out = (float*)d_out;

    const int* src = ei;
    const int* dst = ei + NE;

    // workspace layout (bytes), total 96.93 MB
    char* ws = (char*)d_ws;
    int*    off  = (int*)(ws);                   // 400000
    int*    srt  = (int*)(ws + 400000);          // 6400000 (ends 6.8MB)
    ushort* WT1  = (ushort*)(ws + 7200000);      // 65536
    ushort* WT2  = (ushort*)(ws + 7265536);      // 65536
    ushort* xb   = (ushort*)(ws + 7331072);      // 25600000
    uint*   xf8  = (uint*)(ws + 32931072);       // 12800000 (row-major fp8)
    ushort* aggb = (ushort*)(ws + 45731072);     // 25600000
    ushort* hb   = (ushort*)(ws + 71331072);     // 25600000 (end 96.93MB)
    uchar*  hf8  = (uchar*)xf8;                  // alias: xf8 dead after agg L1
    // CSR-build temporaries (alias aggb region, all dead before agg writes it):
    uint*   pairs = (uint*)aggb;                         // 6400000 (packed 4B)
    int*    hist  = (int*)((char*)aggb + 6400000);       // 196*391*4 = 306544
    ushort* rank8 = (ushort*)((char*)aggb + 6720000);    // 3200000
    int*    gt    = (int*)((char*)aggb + 9920512);       // 1564
    int*    goff  = (int*)((char*)aggb + 9922304);       // 1568

    // ---- CSR build (atomic-free, packed, src-sorted segments) ----
    pA_hist<<<PA_BLOCKS, 256, 0, stream>>>(dst, hist, rank8);
    pS2_colscan<<<NBUCK, 256, 0, stream>>>(hist, gt);
    pS_scan<<<1, 512, 0, stream>>>(gt, goff);
    fused_mid<<<PB_BLOCKS + CX_BLOCKS + CW_BLOCKS, 512, 0, stream>>>(
        src, dst, rank8, hist, goff, pairs, x, xb, xf8,
        W1l, W1r, W2l, W2r, WT1, WT2);
    pC_scatter<<<NBUCK, 256, 0, stream>>>(pairs, goff, off, srt);

    const int gemm_grid = (NN + 127) / 128;

    // ---- layer 1 ----  (single-pass agg: every edge row gathered once)
    agg_csr<<<AGG_GRID, 256, 0, stream>>>(xf8, srt, off, aggb);
    gemm_mfma<1, 1, 1><<<gemm_grid, 512, 0, stream>>>(aggb, xb, WT1, b1, hb, hf8);

    // ---- layer 2 ----
    agg_csr<<<AGG_GRID, 256, 0, stream>>>((const uint*)hf8, srt, off, aggb);
    gemm_mfma<0, 0, 0><<<gemm_grid, 512, 0, stream>>>(aggb, hb, WT2, b2, out, nullptr);
}

// Round 19
// 181.435 us; speedup vs baseline: 1.1907x; 1.0724x over previous
//
#include <hip/hip_runtime.h>

#define NN 100000
#define NE 1600000
#define DF 128
#define NBUCK 391      // ceil(NN/256); bucket b = dst >> 8
#define PA_BLOCKS 196  // ceil(NE / 8192), 32 edges/thread @256
#define PB_BLOCKS 196  // ceil(NE / 8192), 16 edges/thread @512
#define CX_BLOCKS 3125 // NN*DF/8 / 512
#define CW_BLOCKS 64   // 128*256 / 512
#define AGG_GRID 3128  // ceil(NN/32) padded to %8==0

typedef short short8 __attribute__((ext_vector_type(8)));
typedef float floatx4 __attribute__((ext_vector_type(4)));
typedef float floatx2 __attribute__((ext_vector_type(2)));
typedef unsigned int uintx4 __attribute__((ext_vector_type(4)));
typedef unsigned int uintx2 __attribute__((ext_vector_type(2)));
typedef unsigned int uint;
typedef unsigned short ushort;
typedef unsigned char uchar;

// float -> bf16 (RNE; inputs finite)
static __device__ __forceinline__ ushort f2bf(float f) {
    uint u = __builtin_bit_cast(uint, f);
    return (ushort)((u + 0x7fffu + ((u >> 16) & 1u)) >> 16);
}

// ---------------------------------------------------------------------------
// Atomic-free CSR build (R12/R13, best-measured 181.8us): per-edge rank +
// per-block histogram, scans, deterministic packed scatter.
// pairs = ((dst&255)<<17 | src), 4B. R15-R18's src-sorting experiments were
// net-negative (sort cost > sorted-agg gain); reverted.
// ---------------------------------------------------------------------------
__global__ __launch_bounds__(256) void pA_hist(const int* __restrict__ dst,
                                               int* __restrict__ hist,
                                               ushort* __restrict__ rank8) {
    __shared__ int h[NBUCK];
    int tid = threadIdx.x;
    for (int i = tid; i < NBUCK; i += 256) h[i] = 0;
    __syncthreads();
    int eb = blockIdx.x * 8192 + tid;
    #pragma unroll
    for (int k = 0; k < 32; ++k) {
        int e = eb + k * 256;
        if (e < NE) {
            int r = atomicAdd(&h[dst[e] >> 8], 1);
            rank8[e] = (ushort)r;               // rank within (block,bucket)
        }
    }
    __syncthreads();
    int* hrow = hist + blockIdx.x * NBUCK;
    for (int i = tid; i < NBUCK; i += 256) hrow[i] = h[i];
}

// Per-bucket exclusive scan over the 196 block rows: hist -> rel (in place),
// column total -> gt[b]. hist is 306KB, L2-resident.
__global__ __launch_bounds__(256) void pS2_colscan(int* __restrict__ hist,
                                                   int* __restrict__ gt) {
    __shared__ int ps[256];
    int b = blockIdx.x;
    int tid = threadIdx.x;
    int v = (tid < PA_BLOCKS) ? hist[tid * NBUCK + b] : 0;
    ps[tid] = v;
    __syncthreads();
    for (int st = 1; st < 256; st <<= 1) {
        int t = (tid >= st) ? ps[tid - st] : 0;
        __syncthreads();
        ps[tid] += t;
        __syncthreads();
    }
    if (tid < PA_BLOCKS) hist[tid * NBUCK + b] = ps[tid] - v;
    if (tid == 255) gt[b] = ps[255];            // column total
}

// Pass S: exclusive scan of bucket totals -> goff.
__global__ __launch_bounds__(512) void pS_scan(const int* __restrict__ gt,
                                               int* __restrict__ goff) {
    __shared__ int s[512];
    int tid = threadIdx.x;
    int v = (tid < NBUCK) ? gt[tid] : 0;
    s[tid] = v;
    __syncthreads();
    for (int st = 1; st < 512; st <<= 1) {
        int t = (tid >= st) ? s[tid - st] : 0;
        __syncthreads();
        s[tid] += t;
        __syncthreads();
    }
    if (tid < NBUCK) goff[tid] = s[tid] - v;
    if (tid == 0) goff[NBUCK] = NE;
}

// ---------------------------------------------------------------------------
// fused_mid: pB (deterministic 4B-pair scatter) overlapped with conv_x+conv_w.
// pB: lbase[b] = goff[b]+rel_row[b] staged in LDS once; per edge = 3 coalesced
// loads + 1 LDS read + 1 packed store. Zero atomics.
// conv outputs via NT stores (pure streams, no short-term reuse).
// ---------------------------------------------------------------------------
__global__ __launch_bounds__(512) void fused_mid(
        const int* __restrict__ src, const int* __restrict__ dst,
        const ushort* __restrict__ rank8, const int* __restrict__ rel,
        const int* __restrict__ goff, uint* __restrict__ pairs,
        const float* __restrict__ x, ushort* __restrict__ xb, uint* __restrict__ xf8,
        const float* __restrict__ W1l, const float* __restrict__ W1r,
        const float* __restrict__ W2l, const float* __restrict__ W2r,
        ushort* __restrict__ WT1, ushort* __restrict__ WT2) {
    __shared__ int lbase[NBUCK];
    int bid = blockIdx.x;
    int tid = threadIdx.x;
    if (bid < PB_BLOCKS) {
        const int* rel_row = rel + bid * NBUCK;
        for (int i = tid; i < NBUCK; i += 512) lbase[i] = goff[i] + rel_row[i];
        __syncthreads();
        int eb = bid * 8192 + tid;
        #pragma unroll
        for (int k = 0; k < 16; ++k) {
            int e = eb + k * 512;
            if (e < NE) {
                int s = src[e];
                int d = dst[e];
                int b = d >> 8;
                int pos = lbase[b] + (int)rank8[e];
                pairs[pos] = ((uint)(d & 255) << 17) | (uint)s;
            }
        }
    } else if (bid < PB_BLOCKS + CX_BLOCKS) {
        int j = (bid - PB_BLOCKS) * 512 + tid;   // elem group [j*8, j*8+8)
        const float4* xr = (const float4*)x + (size_t)j * 2;
        float4 v0 = xr[0], v1 = xr[1];
        uintx4 ob;
        ob.x = (uint)f2bf(v0.x) | ((uint)f2bf(v0.y) << 16);
        ob.y = (uint)f2bf(v0.z) | ((uint)f2bf(v0.w) << 16);
        ob.z = (uint)f2bf(v1.x) | ((uint)f2bf(v1.y) << 16);
        ob.w = (uint)f2bf(v1.z) | ((uint)f2bf(v1.w) << 16);
        __builtin_nontemporal_store(ob, (uintx4*)xb + j);
        uint pk0 = (uint)__builtin_amdgcn_cvt_pk_fp8_f32(v0.x, v0.y, 0, false);
        pk0 = (uint)__builtin_amdgcn_cvt_pk_fp8_f32(v0.z, v0.w, (int)pk0, true);
        uint pk1 = (uint)__builtin_amdgcn_cvt_pk_fp8_f32(v1.x, v1.y, 0, false);
        pk1 = (uint)__builtin_amdgcn_cvt_pk_fp8_f32(v1.z, v1.w, (int)pk1, true);
        uintx2 pkv = {pk0, pk1};
        __builtin_nontemporal_store(pkv, (uintx2*)xf8 + j);
    } else {
        int id = (bid - PB_BLOCKS - CX_BLOCKS) * 512 + tid;
        int n = id >> 8, k = id & 255;
        float a = (k < 128) ? W1l[k * 128 + n] : W1r[(k - 128) * 128 + n];
        float b = (k < 128) ? W2l[k * 128 + n] : W2r[(k - 128) * 128 + n];
        WT1[id] = f2bf(a);
        WT2[id] = f2bf(b);
    }
}

// Pass C: one block per bucket. LDS degree count + scan -> off[] (coalesced),
// then scatter src into the bucket's ~16KB srt window. pairs read is L2-hot.
__global__ __launch_bounds__(256) void pC_scatter(const uint* __restrict__ pairs,
                                                  const int* __restrict__ goff,
                                                  int* __restrict__ off,
                                                  int* __restrict__ srt) {
    __shared__ int deg[256];
    __shared__ int loc[256];
    int b = blockIdx.x;
    int beg = goff[b], end = goff[b + 1];
    int tid = threadIdx.x;
    deg[tid] = 0;
    __syncthreads();
    for (int i = beg + tid; i < end; i += 256)
        atomicAdd(&deg[pairs[i] >> 17], 1);
    __syncthreads();
    int v = deg[tid];
    loc[tid] = v;
    __syncthreads();
    for (int st = 1; st < 256; st <<= 1) {
        int t = (tid >= st) ? loc[tid - st] : 0;
        __syncthreads();
        loc[tid] += t;
        __syncthreads();
    }
    int excl = loc[tid] - v + beg;     // global CSR offset for node (b<<8)+tid
    int n = (b << 8) + tid;
    if (n < NN) off[n] = excl;
    __syncthreads();
    deg[tid] = excl;                   // reuse as cursor
    __syncthreads();
    for (int i = beg + tid; i < end; i += 256) {
        uint pr = pairs[i];
        int pos = atomicAdd(&deg[pr >> 17], 1);
        srt[pos] = (int)(pr & 0x1FFFFu);
    }
}

// ---------------------------------------------------------------------------
// Mean aggregation, SINGLE PASS over row-major fp8 (R11/R13 design).
// 8 lanes/node x uint4 = full 128B row per edge; 32 nodes/block; srt segment
// LDS-staged once; 8-deep independent gather batches; NT bf16 output.
// Residual cost = random-gather service latency over a 12.8MB working set
// (> 4MB/XCD L2): proven not divergence (R14), not issue-depth (R9), not
// index latency (R10), not sort-fixable at acceptable cost (R15-R18).
// ---------------------------------------------------------------------------
static __device__ __forceinline__ void acc16(floatx2* ac, uint4 v) {
    ac[0] += __builtin_amdgcn_cvt_pk_f32_fp8((int)v.x, false);
    ac[1] += __builtin_amdgcn_cvt_pk_f32_fp8((int)v.x, true);
    ac[2] += __builtin_amdgcn_cvt_pk_f32_fp8((int)v.y, false);
    ac[3] += __builtin_amdgcn_cvt_pk_f32_fp8((int)v.y, true);
    ac[4] += __builtin_amdgcn_cvt_pk_f32_fp8((int)v.z, false);
    ac[5] += __builtin_amdgcn_cvt_pk_f32_fp8((int)v.z, true);
    ac[6] += __builtin_amdgcn_cvt_pk_f32_fp8((int)v.w, false);
    ac[7] += __builtin_amdgcn_cvt_pk_f32_fp8((int)v.w, true);
}

#define AGG_LOOP(IDX)                                            \
    {                                                            \
        int i = lb;                                              \
        for (; i + 8 <= le; i += 8) {                            \
            int idx[8];                                          \
            _Pragma("unroll")                                    \
            for (int k = 0; k < 8; ++k) idx[k] = IDX(i + k);     \
            uint4 v[8];                                          \
            _Pragma("unroll")                                    \
            for (int k = 0; k < 8; ++k) v[k] = f[(size_t)idx[k] * 8]; \
            _Pragma("unroll")                                    \
            for (int k = 0; k < 8; ++k) acc16(ac, v[k]);         \
        }                                                        \
        if (i + 4 <= le) {                                       \
            int idx[4];                                          \
            _Pragma("unroll")                                    \
            for (int k = 0; k < 4; ++k) idx[k] = IDX(i + k);     \
            uint4 v[4];                                          \
            _Pragma("unroll")                                    \
            for (int k = 0; k < 4; ++k) v[k] = f[(size_t)idx[k] * 8]; \
            _Pragma("unroll")                                    \
            for (int k = 0; k < 4; ++k) acc16(ac, v[k]);         \
            i += 4;                                              \
        }                                                        \
        for (; i < le; ++i) {                                    \
            uint4 v = f[(size_t)IDX(i) * 8];                     \
            acc16(ac, v);                                        \
        }                                                        \
    }

__global__ __launch_bounds__(256) void agg_csr(const uint* __restrict__ feat8,
                                               const int* __restrict__ srt,
                                               const int* __restrict__ off,
                                               ushort* __restrict__ aggb) {
    __shared__ int sidx[2048];
    int nb = blockIdx.x * 32;
    if (nb >= NN) return;                        // uniform per block; NN%32==0
    int tid = threadIdx.x;

    int segb = off[nb];
    int nend = nb + 32;
    int sege = (nend < NN) ? off[nend] : NE;
    int stage = min(sege - segb, 2048);
    for (int i = tid; i < stage; i += 256) sidx[i] = srt[segb + i];
    __syncthreads();

    int n = nb + (tid >> 3);
    int l = tid & 7;
    const uint4* f = (const uint4*)feat8 + l;    // row stride = 8 uint4 (128B)

    int beg = off[n];
    int end = (n < NN - 1) ? off[n + 1] : NE;
    int lb = beg - segb, le = end - segb;

    floatx2 ac[8];
    #pragma unroll
    for (int t = 0; t < 8; ++t) ac[t] = (floatx2){0.f, 0.f};

    if (le <= stage) {
        #define IDX_LDS(ii) sidx[ii]
        AGG_LOOP(IDX_LDS)
        #undef IDX_LDS
    } else {
        #define IDX_GBL(ii) srt[segb + (ii)]
        AGG_LOOP(IDX_GBL)
        #undef IDX_GBL
    }

    float inv = 1.0f / fmaxf((float)(end - beg), 1.0f);
    uintx4 o0, o1;
    o0.x = (uint)f2bf(ac[0].x * inv) | ((uint)f2bf(ac[0].y * inv) << 16);
    o0.y = (uint)f2bf(ac[1].x * inv) | ((uint)f2bf(ac[1].y * inv) << 16);
    o0.z = (uint)f2bf(ac[2].x * inv) | ((uint)f2bf(ac[2].y * inv) << 16);
    o0.w = (uint)f2bf(ac[3].x * inv) | ((uint)f2bf(ac[3].y * inv) << 16);
    o1.x = (uint)f2bf(ac[4].x * inv) | ((uint)f2bf(ac[4].y * inv) << 16);
    o1.y = (uint)f2bf(ac[5].x * inv) | ((uint)f2bf(ac[5].y * inv) << 16);
    o1.z = (uint)f2bf(ac[6].x * inv) | ((uint)f2bf(ac[6].y * inv) << 16);
    o1.w = (uint)f2bf(ac[7].x * inv) | ((uint)f2bf(ac[7].y * inv) << 16);
    uintx4* dp = (uintx4*)(aggb + (size_t)n * 128 + l * 16);
    __builtin_nontemporal_store(o0, dp);
    __builtin_nontemporal_store(o1, dp + 1);
}

// ---------------------------------------------------------------------------
// Fused GEMM: C[n,j] = act( [agg|self][n,:] @ WT[j,:] + bias[j] ), K=256.
// 512 threads = 8 waves, 128 rows/block. WT staged in LDS (XOR swizzle, 64KB).
// F8OUT: emit fp8 ROW-MAJOR (single-pass agg input) -> contiguous epilogue.
// ---------------------------------------------------------------------------
template <int RELU, int BF16OUT, int F8OUT>
__global__ __launch_bounds__(512, 4) void gemm_mfma(
        const ushort* __restrict__ aggb, const ushort* __restrict__ selfb,
        const ushort* __restrict__ WT, const float* __restrict__ bias,
        void* __restrict__ outv, uchar* __restrict__ f8out) {
    __shared__ ushort sWT[128 * 256];            // 64KB, swizzled chunks
    const int tid = threadIdx.x;
    const int blk = blockIdx.x;

    #pragma unroll
    for (int it = 0; it < 8; ++it) {
        int flat = it * 512 + tid;               // 0..4095
        int col = flat >> 5;
        int c = flat & 31;
        uint4 v = *(const uint4*)(WT + (size_t)col * 256 + c * 8);
        *(uint4*)&sWT[col * 256 + (c ^ (col & 7)) * 8] = v;
    }

    const int w = tid >> 6;
    const int lane = tid & 63;
    const int m = lane & 15;
    const int q = lane >> 4;

    int node_m = blk * 128 + w * 16 + m;
    int cn = node_m < NN ? node_m : NN - 1;
    const ushort* arow = aggb + (size_t)cn * 128;
    const ushort* xrow = selfb + (size_t)cn * 128;
    short8 a[8];
    #pragma unroll
    for (int kk = 0; kk < 4; ++kk) {
        a[kk]     = *(const short8*)(arow + kk * 32 + q * 8);
        a[4 + kk] = *(const short8*)(xrow + kk * 32 + q * 8);
    }

    __syncthreads();

    floatx4 acc[8];
    #pragma unroll
    for (int t = 0; t < 8; ++t) acc[t] = (floatx4){0.f, 0.f, 0.f, 0.f};

    const int m7 = m & 7;
    #pragma unroll
    for (int kk = 0; kk < 8; ++kk) {
        int cx = (kk * 4 + q) ^ m7;
        #pragma unroll
        for (int t = 0; t < 8; ++t) {
            short8 b = *(const short8*)&sWT[(t * 16 + m) * 256 + cx * 8];
            acc[t] = __builtin_amdgcn_mfma_f32_16x16x32_bf16(a[kk], b, acc[t], 0, 0, 0);
        }
    }

    const int node_base = blk * 128 + w * 16 + q * 4;
    #pragma unroll
    for (int t = 0; t < 8; ++t) {
        int col = t * 16 + m;
        float bj = bias[col];
        #pragma unroll
        for (int r = 0; r < 4; ++r) {
            int node = node_base + r;
            if (node < NN) {
                float v = acc[t][r] + bj;
                if (RELU) v = fmaxf(v, 0.0f);
                if (BF16OUT)
                    ((ushort*)outv)[(size_t)node * 128 + col] = f2bf(v);
                else
                    ((float*)outv)[(size_t)node * 128 + col] = v;
                if (F8OUT) {
                    uint pk = (uint)__builtin_amdgcn_cvt_pk_fp8_f32(v, v, 0, false);
                    f8out[(size_t)node * 128 + col] = (uchar)pk;
                }
            }
        }
    }
}

// ---------------------------------------------------------------------------
extern "C" void kernel_launch(void* const* d_in, const int* in_sizes, int n_in,
                              void* d_out, int out_size, void* d_ws, size_t ws_size,
                              hipStream_t stream) {
    const float* x   = (const float*)d_in[0];
    const int*   ei  = (const int*)d_in[1];
    const float* W1l = (const float*)d_in[2];
    const float* b1  = (const float*)d_in[3];
    const float* W1r = (const float*)d_in[4];
    const float* W2l = (const float*)d_in[5];
    const float* b2  = (const float*)d_in[6];
    const float* W2r = (const float*)d_in[7];
    float*       out = (float*)d_out;

    const int* src = ei;
    const int* dst = ei + NE;

    // workspace layout (bytes), total 96.93 MB
    char* ws = (char*)d_ws;
    int*    off  = (int*)(ws);                   // 400000
    int*    srt  = (int*)(ws + 400000);          // 6400000 (ends 6.8MB)
    ushort* WT1  = (ushort*)(ws + 7200000);      // 65536
    ushort* WT2  = (ushort*)(ws + 7265536);      // 65536
    ushort* xb   = (ushort*)(ws + 7331072);      // 25600000
    uint*   xf8  = (uint*)(ws + 32931072);       // 12800000 (row-major fp8)
    ushort* aggb = (ushort*)(ws + 45731072);     // 25600000
    ushort* hb   = (ushort*)(ws + 71331072);     // 25600000 (end 96.93MB)
    uchar*  hf8  = (uchar*)xf8;                  // alias: xf8 dead after agg L1
    // CSR-build temporaries (alias aggb region, all dead before agg writes it):
    uint*   pairs = (uint*)aggb;                         // 6400000 (packed 4B)
    int*    hist  = (int*)((char*)aggb + 6400000);       // 196*391*4 = 306544
    ushort* rank8 = (ushort*)((char*)aggb + 6720000);    // 3200000
    int*    gt    = (int*)((char*)aggb + 9920512);       // 1564
    int*    goff  = (int*)((char*)aggb + 9922304);       // 1568

    // ---- CSR build (atomic-free, packed) + input conversion ----
    pA_hist<<<PA_BLOCKS, 256, 0, stream>>>(dst, hist, rank8);
    pS2_colscan<<<NBUCK, 256, 0, stream>>>(hist, gt);
    pS_scan<<<1, 512, 0, stream>>>(gt, goff);
    fused_mid<<<PB_BLOCKS + CX_BLOCKS + CW_BLOCKS, 512, 0, stream>>>(
        src, dst, rank8, hist, goff, pairs, x, xb, xf8,
        W1l, W1r, W2l, W2r, WT1, WT2);
    pC_scatter<<<NBUCK, 256, 0, stream>>>(pairs, goff, off, srt);

    const int gemm_grid = (NN + 127) / 128;

    // ---- layer 1 ----  (single-pass agg: every edge row gathered once)
    agg_csr<<<AGG_GRID, 256, 0, stream>>>(xf8, srt, off, aggb);
    gemm_mfma<1, 1, 1><<<gemm_grid, 512, 0, stream>>>(aggb, xb, WT1, b1, hb, hf8);

    // ---- layer 2 ----
    agg_csr<<<AGG_GRID, 256, 0, stream>>>((const uint*)hf8, srt, off, aggb);
    gemm_mfma<0, 0, 0><<<gemm_grid, 512, 0, stream>>>(aggb, hb, WT2, b2, out, nullptr);
}